// Round 1
// 107.272 us; speedup vs baseline: 1.0979x; 1.0979x over previous
//
#include <hip/hip_runtime.h>

// Problem constants (fixed by setup_inputs)
constexpr int B_ = 2, C_ = 256, H_ = 160, W_ = 160;
constexpr int N_ = 128, P_ = 7, S_ = 4;
constexpr float SCALE_ = 0.0625f;
constexpr float TRANS_STD_ = 0.1f;
constexpr int HW_ = H_ * W_;           // 25600
constexpr int CELLS_ = P_ * P_;        // 49
constexpr int NCELLS_ = N_ * CELLS_;   // 6272
constexpr int CPB_ = 8;                // cells per 256-thread block (2/wave)
constexpr int POOL_BLOCKS_ = NCELLS_ / CPB_;   // 784 = 8 XCDs * 98

// ---- bf16 helpers (raw ushort payload; RNE) ------------------------------
__device__ inline unsigned short f32_to_bf16(float f) {
    unsigned int u = __float_as_uint(f);
    u += 0x7FFFu + ((u >> 16) & 1u);   // round-to-nearest-even
    return (unsigned short)(u >> 16);
}
// a packed u32 holds two bf16 channels: lo = ch 2j, hi = ch 2j+1
__device__ inline float bf_lo(unsigned int u) { return __uint_as_float(u << 16); }
__device__ inline float bf_hi(unsigned int u) { return __uint_as_float(u & 0xFFFF0000u); }

// --------------------------------------------------------------------------
// Kernel 1: NCHW f32 -> NHWC bf16. 64(px) x 64(ch) tiles, 256 threads.
// (unchanged — runs near its 78.6 MB BW floor)
// --------------------------------------------------------------------------
constexpr int TP_ = 64, TC_ = 64, LDSC_ = TC_ + 4;

__global__ __launch_bounds__(256) void transpose_bf16(
    const float* __restrict__ in, unsigned short* __restrict__ out) {
    __shared__ unsigned short tile[TP_][LDSC_];      // [pixel][channel]
    const int p0 = blockIdx.x * TP_;
    const int c0 = blockIdx.y * TC_;
    const int b  = blockIdx.z;
    const int tx = threadIdx.x & 15;                 // 0..15
    const int ty = threadIdx.x >> 4;                 // 0..15

#pragma unroll
    for (int k = 0; k < 4; ++k) {
        const int c  = c0 + ty + 16 * k;             // global channel
        const int lp = 4 * tx;                       // tile pixel base
        const float4 v = *(const float4*)
            &in[((size_t)b * C_ + c) * HW_ + p0 + lp];
        const int lc = ty + 16 * k;
        tile[lp + 0][lc] = f32_to_bf16(v.x);
        tile[lp + 1][lc] = f32_to_bf16(v.y);
        tile[lp + 2][lc] = f32_to_bf16(v.z);
        tile[lp + 3][lc] = f32_to_bf16(v.w);
    }
    __syncthreads();
#pragma unroll
    for (int k = 0; k < 4; ++k) {
        const int lp = ty + 16 * k;
        const int p  = p0 + lp;
        const ushort4 w = *(const ushort4*)&tile[lp][4 * tx];
        *(ushort4*)&out[((size_t)b * HW_ + p) * C_ + c0 + 4 * tx] = w;
    }
}

// --------------------------------------------------------------------------
// Shared per-cell geometry computation.
// --------------------------------------------------------------------------
struct CellGeom {
    int   b;
    float wstart, hstart, sw, sh;
};

__device__ inline CellGeom cell_geom(const float* __restrict__ rois,
                                     const float* __restrict__ offset,
                                     int n, int ph, int pw, int cell) {
    const float* r = rois + n * 5;
    CellGeom g;
    g.b = (int)r[0];
    // jnp.round is round-half-even -> rintf (default rounding mode)
    const float rsw = rintf(r[1]) * SCALE_ - 0.5f;
    const float rsh = rintf(r[2]) * SCALE_ - 0.5f;
    const float rew = (rintf(r[3]) + 1.0f) * SCALE_ - 0.5f;
    const float reh = (rintf(r[4]) + 1.0f) * SCALE_ - 0.5f;
    const float rw = fmaxf(rew - rsw, 0.1f);
    const float rh = fmaxf(reh - rsh, 0.1f);
    const float bw = rw / (float)P_;
    const float bh = rh / (float)P_;
    g.sw = bw / (float)S_;
    g.sh = bh / (float)S_;
    // part_h == ph, part_w == pw (PART == P == 7)
    const float tx = offset[(n * 2 + 0) * CELLS_ + cell] * TRANS_STD_;
    const float ty = offset[(n * 2 + 1) * CELLS_ + cell] * TRANS_STD_;
    g.wstart = (float)pw * bw + rsw + tx * rw;
    g.hstart = (float)ph * bh + rsh + ty * rh;
    return g;
}

// --------------------------------------------------------------------------
// Kernel 2 (v2): pooling over bf16 NHWC image.
//  - 256 threads = 4 waves; each wave handles 2 cells (half-wave each).
//  - Lane owns 8 channels -> uint4 (16 B) loads, 1 KB/wave per corner.
//  - XCD-chunked blockIdx swizzle: each XCD owns 16 consecutive rois
//    (~3.3 MB of image region) so gather loads hit its private L2.
//  - Branchless validity (mask folded into bilinear weights) so the two
//    half-wave cells never serialize on divergent control flow.
// --------------------------------------------------------------------------
__global__ __launch_bounds__(256) void pool_nhwc_bf16_v2(
    const unsigned short* __restrict__ img,   // (B,H,W,C) bf16
    const float* __restrict__ rois,
    const float* __restrict__ offset,
    float* __restrict__ out) {
    // bijective chunked swizzle: 784 % 8 == 0, so chunk size = 98
    const int bid = blockIdx.x;
    const int swz = (bid & 7) * (POOL_BLOCKS_ / 8) + (bid >> 3);

    const int wave = threadIdx.x >> 6;   // 0..3
    const int lane = threadIdx.x & 63;
    const int half = lane >> 5;          // 0/1: which cell in this wave
    const int cl   = lane & 31;          // channel-octet index (8 ch each)

    const int cellg = swz * CPB_ + wave * 2 + half;  // 0..6271
    const int n     = cellg / CELLS_;
    const int cell  = cellg - n * CELLS_;
    const int ph    = cell / P_;
    const int pw    = cell - ph * P_;

    const CellGeom g = cell_geom(rois, offset, n, ph, pw, cell);
    const unsigned short* base =
        img + (size_t)g.b * ((size_t)HW_ * C_) + 8 * cl;

    float acc[8] = {0.f, 0.f, 0.f, 0.f, 0.f, 0.f, 0.f, 0.f};
    float count = 0.0f;

#pragma unroll
    for (int iy = 0; iy < S_; ++iy) {
        const float y = g.hstart + (float)iy * g.sh;
#pragma unroll
        for (int ix = 0; ix < S_; ++ix) {
            const float x = g.wstart + (float)ix * g.sw;
            const bool valid = (x >= -0.5f) & (x <= (float)W_ - 0.5f) &
                               (y >= -0.5f) & (y <= (float)H_ - 0.5f);
            const float vm = valid ? 1.0f : 0.0f;
            count += vm;
            const float xc = fminf(fmaxf(x, 0.0f), (float)(W_ - 1));
            const float yc = fminf(fmaxf(y, 0.0f), (float)(H_ - 1));
            const float x0f = floorf(xc), y0f = floorf(yc);
            const float dx = xc - x0f, dy = yc - y0f;
            const int x0 = (int)x0f,       y0 = (int)y0f;
            const int x1 = (int)ceilf(xc), y1 = (int)ceilf(yc);
            const float w00 = vm * (1.f - dx) * (1.f - dy);
            const float w01 = vm * (1.f - dx) * dy;
            const float w10 = vm * dx * (1.f - dy);
            const float w11 = vm * dx * dy;
            const uint4 u00 = *(const uint4*)(base + (size_t)(y0 * W_ + x0) * C_);
            const uint4 u01 = *(const uint4*)(base + (size_t)(y1 * W_ + x0) * C_);
            const uint4 u10 = *(const uint4*)(base + (size_t)(y0 * W_ + x1) * C_);
            const uint4 u11 = *(const uint4*)(base + (size_t)(y1 * W_ + x1) * C_);
            acc[0] += w00 * bf_lo(u00.x) + w01 * bf_lo(u01.x) +
                      w10 * bf_lo(u10.x) + w11 * bf_lo(u11.x);
            acc[1] += w00 * bf_hi(u00.x) + w01 * bf_hi(u01.x) +
                      w10 * bf_hi(u10.x) + w11 * bf_hi(u11.x);
            acc[2] += w00 * bf_lo(u00.y) + w01 * bf_lo(u01.y) +
                      w10 * bf_lo(u10.y) + w11 * bf_lo(u11.y);
            acc[3] += w00 * bf_hi(u00.y) + w01 * bf_hi(u01.y) +
                      w10 * bf_hi(u10.y) + w11 * bf_hi(u11.y);
            acc[4] += w00 * bf_lo(u00.z) + w01 * bf_lo(u01.z) +
                      w10 * bf_lo(u10.z) + w11 * bf_lo(u11.z);
            acc[5] += w00 * bf_hi(u00.z) + w01 * bf_hi(u01.z) +
                      w10 * bf_hi(u10.z) + w11 * bf_hi(u11.z);
            acc[6] += w00 * bf_lo(u00.w) + w01 * bf_lo(u01.w) +
                      w10 * bf_lo(u10.w) + w11 * bf_lo(u11.w);
            acc[7] += w00 * bf_hi(u00.w) + w01 * bf_hi(u01.w) +
                      w10 * bf_hi(u10.w) + w11 * bf_hi(u11.w);
        }
    }

    const float inv = 1.0f / fmaxf(count, 1.0f);
    // out[(n*C + c)*49 + cell], c = 8*cl .. 8*cl+7
    const size_t obase = ((size_t)n * C_ + 8 * cl) * CELLS_ + cell;
#pragma unroll
    for (int j = 0; j < 8; ++j)
        out[obase + (size_t)j * CELLS_] = acc[j] * inv;
}

// --------------------------------------------------------------------------
// Fallback: pooling straight from NCHW f32 input (only if ws too small).
// --------------------------------------------------------------------------
__global__ __launch_bounds__(256) void pool_nchw(
    const float* __restrict__ img,   // (B,C,H,W)
    const float* __restrict__ rois,
    const float* __restrict__ offset,
    float* __restrict__ out) {
    const int blk  = blockIdx.x;
    const int n    = blk / CELLS_;
    const int cell = blk % CELLS_;
    const int ph   = cell / P_;
    const int pw   = cell % P_;
    const int c    = threadIdx.x;    // 0..255

    const CellGeom g = cell_geom(rois, offset, n, ph, pw, cell);
    const float* base = img + ((size_t)g.b * C_ + c) * HW_;

    float acc = 0.0f;
    float count = 0.0f;

#pragma unroll
    for (int iy = 0; iy < S_; ++iy) {
        const float y = g.hstart + (float)iy * g.sh;
#pragma unroll
        for (int ix = 0; ix < S_; ++ix) {
            const float x = g.wstart + (float)ix * g.sw;
            if (x < -0.5f || x > (float)W_ - 0.5f ||
                y < -0.5f || y > (float)H_ - 0.5f)
                continue;
            count += 1.0f;
            const float xc = fminf(fmaxf(x, 0.0f), (float)(W_ - 1));
            const float yc = fminf(fmaxf(y, 0.0f), (float)(H_ - 1));
            const float x0f = floorf(xc), y0f = floorf(yc);
            const float dx = xc - x0f, dy = yc - y0f;
            const int x0 = (int)x0f,       y0 = (int)y0f;
            const int x1 = (int)ceilf(xc), y1 = (int)ceilf(yc);
            const float w00 = (1.f - dx) * (1.f - dy);
            const float w01 = (1.f - dx) * dy;
            const float w10 = dx * (1.f - dy);
            const float w11 = dx * dy;
            acc += w00 * base[y0 * W_ + x0] + w01 * base[y1 * W_ + x0] +
                   w10 * base[y0 * W_ + x1] + w11 * base[y1 * W_ + x1];
        }
    }

    out[((size_t)n * C_ + c) * CELLS_ + cell] = acc / fmaxf(count, 1.0f);
}

// --------------------------------------------------------------------------
extern "C" void kernel_launch(void* const* d_in, const int* in_sizes, int n_in,
                              void* d_out, int out_size, void* d_ws, size_t ws_size,
                              hipStream_t stream) {
    const float* inp    = (const float*)d_in[0];
    const float* rois   = (const float*)d_in[1];
    const float* offset = (const float*)d_in[2];
    float* out = (float*)d_out;

    const size_t need = (size_t)B_ * HW_ * C_ * sizeof(unsigned short); // 26.2 MB
    if (ws_size >= need) {
        unsigned short* img_nhwc = (unsigned short*)d_ws;
        dim3 tg(HW_ / TP_, C_ / TC_, B_);   // (400, 4, 2)
        transpose_bf16<<<tg, 256, 0, stream>>>(inp, img_nhwc);
        pool_nhwc_bf16_v2<<<POOL_BLOCKS_, 256, 0, stream>>>(img_nhwc, rois, offset, out);
    } else {
        pool_nchw<<<N_ * CELLS_, 256, 0, stream>>>(inp, rois, offset, out);
    }
}